// Round 2
// baseline (83.144 us; speedup 1.0000x reference)
//
#include <hip/hip_runtime.h>

// KAN layer: out[b,o] = sum_i [ sum_g w[o,i,g]*exp(-|tanh(x[b,i])-grid[g]|*s[o,i])
//                               + ba[o,i]*tanh(x[b,i]) ]
// Factorization: exp(-s|xn-g|) = exp(-s*xn)*[w*e^{s*g}]   (g <= xn)
//                              = exp(+s*xn)*[w*e^{-s*g}]  (g >  xn)
// Prefix/suffix tables per (o,i) over the 5 split points k (xn in (-1,1) =>
// k in [2,6]); per (b,o,i): 2 exp2 + 3 fma + one 8B table read (L2-hot).
//
// R7: occupancy 1->4 waves/SIMD -> 80.5 us. R8: VALU-slot scalarization ->
// 82.3 us (neutral within noise => loop is latency-bound, not issue-bound).
// R9 (this): push occupancy to 8 waves/SIMD. BT=1, grid=1024 blocks
// (256 bg x 4 ot), __launch_bounds__(512,8) caps VGPR<=64 -> 4 blocks/CU.
// ot in low blockIdx bits => XCD = blk&7 sees exactly one o-tile => per-XCD
// L2 holds only its 640KB T-slice + 128KB sbt-slice + xnk. Cost: sbt L2
// traffic doubles (64->128MB); bet: latency hiding dominates (R6->R7 trend).
// Structural harness floor measured R5: ~72.6 us.

#define B_   256
#define OUT_ 256
#define IN_  256
#define G_   8
#define NK   5           // k' = k-2
#define BT   1           // b's per main block
#define OT   64          // o-tile = one wave width
#define NW   8           // waves per main block
#define IW   (IN_/NW)    // 32 i's per wave

// ---------------------------------------------------------------------------
// Kernel 1 (prep), grid 256 x 256:
//  part A: idx=(b,i) i-fast  -> xn=tanh(x), precomputed T-row. Coalesced R/W.
//  part B: i=blockIdx, o=tid -> per-(o,i) tables; stores coalesced 512B/wave
//          (T layout [k'][i][o], o fast, matching main's reads).
// ---------------------------------------------------------------------------
__global__ __launch_bounds__(256) void kan_prep(
        const float* __restrict__ x,
        const float* __restrict__ w,
        const float* __restrict__ sc,
        const float* __restrict__ ba,
        const float* __restrict__ grid,
        float2* __restrict__ xnk,
        float2* __restrict__ sbt,
        float2* __restrict__ T)
{
    float g[G_];
#pragma unroll
    for (int j = 0; j < G_; ++j) g[j] = grid[j];   // uniform broadcast loads

    // ---- part A: one (b,i) per thread, i fast -> coalesced
    {
        const int idx = blockIdx.x * 256 + threadIdx.x;
        const float xn = tanhf(x[idx]);
        int k = 0;
#pragma unroll
        for (int j = 0; j < G_; ++j) k += (g[j] <= xn) ? 1 : 0;
        k = min(max(k, 2), 6) - 2;                 // 0..4
        const int row = k * IN_ + (idx & (IN_ - 1));
        xnk[idx] = make_float2(xn, __int_as_float(row * OUT_));  // pre-scaled
    }

    // ---- part B: one i per block, o = tid -> all stores coalesced
    {
        const int i = blockIdx.x;
        const int o = threadIdx.x;
        const int base = o * IN_ + i;              // strided reads (L2-hot)
        const float s  = sc[base];
        const float bv = ba[base];

        float Ep[G_], Em[G_];
#pragma unroll
        for (int j = 0; j < G_; ++j) {
            const float wv = w[base * G_ + j];
            const float t  = s * g[j];
            Ep[j] = wv * __expf(t);
            Em[j] = wv * __expf(-t);
        }
#pragma unroll
        for (int kk = 0; kk < NK; ++kk) {
            const int k = kk + 2;
            float A = 0.f, Bv = 0.f;
#pragma unroll
            for (int j = 0; j < G_; ++j) {
                if (j < k) A += Ep[j]; else Bv += Em[j];   // static split
            }
            T[(kk * IN_ + i) * OUT_ + o] = make_float2(A, Bv);  // 512B/wave
        }
        sbt[i * OUT_ + o] = make_float2(s * 1.44269504088896340736f, bv);
    }
}

// ---------------------------------------------------------------------------
// Kernel 2 (main): grid = 256 b-groups x 4 o-tiles = 1024 blocks,
// 512 threads = 8 waves (4 blocks/CU -> 8 waves/SIMD). Wave ig owns 32 i's,
// 64 o-lanes, 1 b. Full i-reduction via LDS tree -> direct d_out store.
// Per (b,o,i): 1 LDS broadcast + 2 L2 8B reads + 2 exp2 + 3 fma.
// ---------------------------------------------------------------------------
__global__ __launch_bounds__(512, 8) void kan_main(
        const float2* __restrict__ xnk,
        const float2* __restrict__ sbt,
        const float2* __restrict__ T,
        float* __restrict__ out)
{
    const int lane = threadIdx.x & 63;
    const int igrp = threadIdx.x >> 6;          // 0..7
    const int ot   = blockIdx.x & 3;            // 4 o-tiles (low bits: XCD-slice)
    const int b0   = blockIdx.x >> 2;           // 256 b's
    const int o    = ot * OT + lane;

    __shared__ float2 sxk[IN_];                 // 2 KB: (xn, T-elem-row) per i
    __shared__ float  sacc[NW][OT];             // 2 KB: per-wave partials

    if (threadIdx.x < IN_) {
        sxk[threadIdx.x] = xnk[b0 * IN_ + threadIdx.x];   // coalesced 8B
    }
    __syncthreads();

    float acc = 0.f;
    const int i0 = igrp * IW;

#pragma unroll 4
    for (int ii = 0; ii < IW; ++ii) {
        const int i = i0 + ii;
        const float2 sb = sbt[i * OUT_ + o];    // 512B/wave, L2-hot
        const float2 xk = sxk[i];               // wave-uniform LDS broadcast
        const float xn  = xk.x;
        const float2 rec = T[__float_as_int(xk.y) + o];  // 512B/wave, L2
        const float t = sb.x * xn;              // s*log2e*xn
        float a = fmaf(sb.y, xn, acc);          // + ba*xn
        a       = fmaf(exp2f(-t), rec.x, a);    // + e^{-s*xn} * A[k]
        acc     = fmaf(exp2f(t),  rec.y, a);    // + e^{+s*xn} * B[k]
    }

    sacc[igrp][lane] = acc;
    __syncthreads();

    if (threadIdx.x < OT) {
        const int l = threadIdx.x;
        float s = 0.f;
#pragma unroll
        for (int wv = 0; wv < NW; ++wv) s += sacc[wv][l];
        out[b0 * OUT_ + ot * OT + l] = s;       // coalesced, full overwrite
    }
}

// ---------------------------------------------------------------------------
extern "C" void kernel_launch(void* const* d_in, const int* in_sizes, int n_in,
                              void* d_out, int out_size, void* d_ws, size_t ws_size,
                              hipStream_t stream)
{
    const float* x    = (const float*)d_in[0];
    const float* w    = (const float*)d_in[1];   // (OUT, IN, G)
    const float* sc   = (const float*)d_in[2];   // (OUT, IN)
    const float* ba   = (const float*)d_in[3];   // (OUT, IN)
    const float* grid = (const float*)d_in[4];   // (G)
    float* out = (float*)d_out;

    // ws: xnk 512KB | sbt 512KB | T 2.5MB   (3.5 MB total)
    char* ws = (char*)d_ws;
    float2* xnk = (float2*)(ws);
    float2* sbt = (float2*)(ws + 512 * 1024);
    float2* T   = (float2*)(ws + 1024 * 1024);

    kan_prep<<<IN_, 256, 0, stream>>>(x, w, sc, ba, grid, xnk, sbt, T);
    kan_main<<<B_ * (OUT_ / OT) / BT, 512, 0, stream>>>(xnk, sbt, T, out);
}